// Round 1
// baseline (203.982 us; speedup 1.0000x reference)
//
#include <hip/hip_runtime.h>

// out[b,o,i,j] = sum_c | sum_{ti,tj} K[o,0,ti,tj] * x[b,c,(i+5-ti)&127,(j+5-tj)&127] |
// B=8 C=16 H=W=128 O=32 KS=9. Derived from the FFT reference:
// fftshift/ifftshift cancel for even N; real*real => field is real => abs = fabsf.

#define B_ 8
#define C_ 16
#define H_ 128
#define O_ 32
#define TH 16   // output rows per block
#define TW 64   // output cols per block (16 threads x 4 px)
#define GO 8    // output channels per block
#define LR 24   // TH + 8 halo rows (i-3..i+5)
#define LC 72   // TW + 8 halo cols

__global__ __launch_bounds__(256)
void optical_conv_69698729279498(const float* __restrict__ x,
                                 const float* __restrict__ kern,
                                 float* __restrict__ out) {
    __shared__ __align__(16) float lds[LR * LC];  // 1728 floats = 6.75 KB

    const int tx = threadIdx.x;              // 0..15 -> 4 cols each
    const int ty = threadIdx.y;              // 0..15 -> row
    const int tid = ty * 16 + tx;
    const int og = blockIdx.x;               // 0..3  o-group
    const int tile = blockIdx.y;             // 0..15 spatial tile
    const int b = blockIdx.z;                // 0..7
    const int c0 = (tile & 1) * TW;
    const int r0 = (tile >> 1) * TH;
    const int obase = og * GO;

    float acc[GO][4];
#pragma unroll
    for (int o = 0; o < GO; ++o)
#pragma unroll
        for (int p = 0; p < 4; ++p) acc[o][p] = 0.f;

    for (int c = 0; c < C_; ++c) {
        __syncthreads();  // protect LDS from previous iteration's readers
        // stage 24x72 halo tile (circular wrap via &127)
        const float* xc = x + ((size_t)(b * C_ + c)) * H_ * H_;
        for (int idx = tid; idx < LR * LC; idx += 256) {
            int rr = idx / LC;
            int cc = idx - rr * LC;
            int gr = (r0 - 3 + rr) & 127;
            int gc = (c0 - 3 + cc) & 127;
            lds[idx] = xc[(gr << 7) + gc];
        }
        __syncthreads();

        float f[GO][4];
#pragma unroll
        for (int o = 0; o < GO; ++o)
#pragma unroll
            for (int p = 0; p < 4; ++p) f[o][p] = 0.f;

        for (int ti = 0; ti < 9; ++ti) {
            // window: output row i=r0+ty needs lds row ty+8-ti,
            // cols 4tx + (p+8-tj), p in [0,4), tj in [0,9) -> 12 floats
            const float4* wp = (const float4*)&lds[(ty + 8 - ti) * LC + 4 * tx];
            float4 w0 = wp[0], w1 = wp[1], w2 = wp[2];
            float xw[12] = {w0.x, w0.y, w0.z, w0.w,
                            w1.x, w1.y, w1.z, w1.w,
                            w2.x, w2.y, w2.z, w2.w};
            const float* kbase = kern + ti * 9;   // kernel[o,0,ti,tj]
#pragma unroll
            for (int o = 0; o < GO; ++o) {
                const float* kp = kbase + (obase + o) * (C_ * 81);
#pragma unroll
                for (int tj = 0; tj < 9; ++tj) {
                    float kv = kp[tj];  // wave-uniform -> s_load
#pragma unroll
                    for (int p = 0; p < 4; ++p)
                        f[o][p] = fmaf(xw[p + 8 - tj], kv, f[o][p]);
                }
            }
        }
#pragma unroll
        for (int o = 0; o < GO; ++o)
#pragma unroll
            for (int p = 0; p < 4; ++p) acc[o][p] += fabsf(f[o][p]);
    }

    const int orow = r0 + ty;
    const int ocol = c0 + 4 * tx;
#pragma unroll
    for (int o = 0; o < GO; ++o) {
        float4 v = make_float4(acc[o][0], acc[o][1], acc[o][2], acc[o][3]);
        *(float4*)&out[((size_t)((b * O_) + obase + o) * H_ + orow) * H_ + ocol] = v;
    }
}

extern "C" void kernel_launch(void* const* d_in, const int* in_sizes, int n_in,
                              void* d_out, int out_size, void* d_ws, size_t ws_size,
                              hipStream_t stream) {
    const float* x = (const float*)d_in[0];      // [8,16,128,128]
    const float* kern = (const float*)d_in[1];   // [32,16,9,9]
    float* out = (float*)d_out;                  // [8,32,128,128]
    dim3 block(16, 16);
    dim3 grid(4, 16, 8);   // o-groups x tiles x batch = 512 blocks
    hipLaunchKernelGGL(optical_conv_69698729279498, grid, block, 0, stream,
                       x, kern, out);
}